// Round 2
// baseline (136.688 us; speedup 1.0000x reference)
//
#include <hip/hip_runtime.h>
#include <hip/hip_bf16.h>
#include <stdint.h>

typedef __attribute__((ext_vector_type(8))) short short8;
typedef __attribute__((ext_vector_type(4))) float f32x4;
typedef uint32_t u32;
typedef uint16_t u16;

#define LOG2E 1.4426950408889634f

// B=4, N=2048, Cin=256, F=64, H=4
// Pipeline (4 kernels):
//  KA k_pre : pack adj bits | WT/Wlb bf16 cvt | fdots (self-computed wa) -> A,B,f2a,f2b
//  KB k_mid : proj (h^T bf16, MFMA)  ||  colsum (D_j via max(A_i*C_j, B_i*D_j)) -> Ca,Db
//  KC k_pv  : P-tile in-register (no trans!), MFMA PV, relu -> cat bf16
//  KD k_out : cat @ Wl^T + bias, leaky -> out f32
//
// ws layout (bytes):
//  adjw : 0x000000 u32 [2048*64]    512KB  row-major packed adjacency bits
//  hT   : 0x080000 bf16[16][64][2048] 4MB  per-(b,h) h transposed [f][n]
//  cat  : 0x480000 bf16[4][2048][256] 4MB  relu(hp) concat heads
//  Aarr : 0x880000 f32 [16][2048]   128KB  exp2(f1*log2e)
//  Barr : 0x8A0000 f32              128KB  exp2(0.2*f1*log2e)
//  f2a  : 0x8C0000 f32              128KB  f2*log2e
//  f2b  : 0x8E0000 f32              128KB  0.2*f2*log2e
//  Ca   : 0x900000 f32              128KB  exp2(f2a)/D_j
//  Db   : 0x920000 f32              128KB  exp2(f2b)/D_j
//  WT   : 0x940000 bf16[4][64][256] 128KB  W transposed [h][f][c]
//  Wlb  : 0x960000 bf16[64][256]     32KB

__device__ __forceinline__ u16 f2bf(float f){
  union{float f; u32 u;} x; x.f = f;
  u32 r = x.u + 0x7FFFu + ((x.u >> 16) & 1u);
  return (u16)(r >> 16);
}
__device__ __forceinline__ u32 pkbf(float a, float b){
  __hip_bfloat162 h = __float22bfloat162_rn(float2{a, b});
  union{ __hip_bfloat162 h; u32 u; } cv; cv.h = h;
  return cv.u;
}
__device__ __forceinline__ float dot4(float4 a, float4 b){
  return a.x*b.x + a.y*b.y + a.z*b.z + a.w*b.w;
}

// ---------------- KA: pack || prep || fdots ----------------
__global__ __launch_bounds__(256) void k_pre(const int* __restrict__ adj, const float* __restrict__ x,
      const float* __restrict__ W, const float* __restrict__ a1, const float* __restrict__ a2,
      const float* __restrict__ Wl,
      u32* __restrict__ adjw, float* __restrict__ Aarr, float* __restrict__ Barr,
      float* __restrict__ f2a, float* __restrict__ f2b,
      u16* __restrict__ WT, u16* __restrict__ Wlb){
  __shared__ float waL[2][1024];
  int bid = blockIdx.x;
  int t = threadIdx.x;

  if (bid < 16384){                       // --- pack adj into bitmask ---
    int idx = bid*256 + t;
    int v = adj[idx];
    unsigned long long m = __ballot(v > 0);
    int lane = t & 63;
    if (lane == 0)       adjw[idx >> 5] = (u32)(m & 0xFFFFFFFFull);
    else if (lane == 32) adjw[idx >> 5] = (u32)(m >> 32);
    return;
  }
  if (bid < 16448){                       // --- WT / Wlb bf16 conversion ---
    int tt = (bid - 16384)*256 + t;
    for (int i = tt; i < 4*64*256; i += 16384){
      int h = i >> 14, f = (i >> 8) & 63, c = i & 255;
      WT[i] = f2bf(W[(h*256 + c)*64 + f]);
    }
    for (int i = tt; i < 64*256; i += 16384) Wlb[i] = f2bf(Wl[i]);
    return;
  }
  // --- fdots: 128 blocks, 64 rows each; self-computed wa in LDS ---
  int rblk = bid - 16448;
  #pragma unroll
  for (int p = 0; p < 4; p++){
    int idx = p*256 + t;                  // idx = h*256 + c in [0,1024)
    int h = idx >> 8;
    const float* wrow = W + (size_t)idx*64;
    float s1 = 0.f, s2 = 0.f;
    #pragma unroll
    for (int f = 0; f < 64; f += 4){
      float4 wv = *(const float4*)(wrow + f);
      float4 v1 = *(const float4*)(a1 + h*64 + f);
      float4 v2 = *(const float4*)(a2 + h*64 + f);
      s1 += dot4(wv, v1); s2 += dot4(wv, v2);
    }
    waL[0][idx] = s1; waL[1][idx] = s2;
  }
  __syncthreads();
  int w = t >> 6, l = t & 63;
  for (int rr = 0; rr < 16; rr++){
    int gr = rblk*64 + w*16 + rr;         // global row [0,8192)
    float4 xv = *(const float4*)(x + (size_t)gr*256 + l*4);
    #pragma unroll
    for (int h = 0; h < 4; h++){
      float p1 = dot4(xv, *(const float4*)&waL[0][h*256 + l*4]);
      float p2 = dot4(xv, *(const float4*)&waL[1][h*256 + l*4]);
      #pragma unroll
      for (int m = 32; m > 0; m >>= 1){ p1 += __shfl_xor(p1, m); p2 += __shfl_xor(p2, m); }
      if (l == 0){
        int b = gr >> 11, n = gr & 2047;
        int o = (b*4 + h)*2048 + n;
        float fa = p1 * LOG2E;
        Aarr[o] = __builtin_amdgcn_exp2f(fa);
        Barr[o] = __builtin_amdgcn_exp2f(0.2f*fa);
        f2a[o] = p2 * LOG2E;
        f2b[o] = p2 * (0.2f*LOG2E);
      }
    }
  }
}

// ---------------- KB: proj || colsum ----------------
__global__ __launch_bounds__(256) void k_mid(const float* __restrict__ x, const u16* __restrict__ WT,
      u16* __restrict__ hT, const u32* __restrict__ adjw,
      const float* __restrict__ Aarr, const float* __restrict__ Barr,
      const float* __restrict__ f2a, const float* __restrict__ f2b,
      float* __restrict__ Ca, float* __restrict__ Db){
  __shared__ float AL[2048], BL[2048];
  __shared__ float part[4][64];
  int bid = blockIdx.x;
  int t = threadIdx.x;
  int w = t >> 6, l = t & 63;

  if (bid < 512){                         // --- proj: h = x @ W, write hT[bh][f][n] bf16 ---
    int rt = bid & 127, cb = bid >> 7;
    int rA = rt*64 + w*16 + (l & 15);
    int kg = (l >> 4) * 8;
    f32x4 acc[4] = {};
    const float* xrow = x + (size_t)rA * 256;
    #pragma unroll
    for (int ks = 0; ks < 8; ks++){
      int c = ks*32 + kg;
      float4 xa = *(const float4*)(xrow + c);
      float4 xb = *(const float4*)(xrow + c + 4);
      union{u32 w[4]; short8 v;} A;
      A.w[0] = pkbf(xa.x, xa.y); A.w[1] = pkbf(xa.z, xa.w);
      A.w[2] = pkbf(xb.x, xb.y); A.w[3] = pkbf(xb.z, xb.w);
      #pragma unroll
      for (int q = 0; q < 4; q++){
        int col = cb*64 + q*16 + (l & 15);
        short8 Bf = *(const short8*)(WT + (size_t)col*256 + c);
        acc[q] = __builtin_amdgcn_mfma_f32_16x16x32_bf16(A.v, Bf, acc[q], 0, 0, 0);
      }
    }
    int rb = rt*64 + w*16 + (l >> 4)*4;
    int b = rb >> 11, n = rb & 2047;
    #pragma unroll
    for (int q = 0; q < 4; q++){
      int fp = cb*64 + q*16 + (l & 15);
      u32 p0 = pkbf(acc[q][0], acc[q][1]);
      u32 p1 = pkbf(acc[q][2], acc[q][3]);
      u16* dst = hT + ((size_t)(b*4 + (fp >> 6))*64 + (fp & 63))*2048 + n;
      *(uint2*)dst = uint2{p0, p1};
    }
    return;
  }
  // --- colsum: D_j = sum_i bit * max(A_i*C_j, B_i*D_j); write Ca=C/D, Db=D̄/D ---
  int id = bid - 512;
  int jt = id & 31, bh = id >> 5;
  {
    const float4* As = (const float4*)(Aarr + bh*2048);
    const float4* Bs = (const float4*)(Barr + bh*2048);
    ((float4*)AL)[t]       = As[t];
    ((float4*)AL)[t + 256] = As[t + 256];
    ((float4*)BL)[t]       = Bs[t];
    ((float4*)BL)[t + 256] = Bs[t + 256];
  }
  int j = jt*64 + l;
  float Cj = __builtin_amdgcn_exp2f(f2a[bh*2048 + j]);
  float Dj = __builtin_amdgcn_exp2f(f2b[bh*2048 + j]);
  int wi = jt*2 + (l >> 5), sh = l & 31;
  __syncthreads();
  const u32* aw = adjw + wi;
  float acc0 = 0.f, acc1 = 0.f;
  int i0 = w * 512;
  #pragma unroll 8
  for (int i = i0; i < i0 + 512; i += 2){
    u32 w0 = aw[(size_t)i*64];
    u32 w1 = aw[(size_t)(i+1)*64];
    float v0 = fmaxf(AL[i]*Cj,   BL[i]*Dj);
    float v1 = fmaxf(AL[i+1]*Cj, BL[i+1]*Dj);
    acc0 = fmaf(v0, (float)((w0 >> sh) & 1u), acc0);
    acc1 = fmaf(v1, (float)((w1 >> sh) & 1u), acc1);
  }
  part[w][l] = acc0 + acc1;
  __syncthreads();
  if (t < 64){
    float D = part[0][l] + part[1][l] + part[2][l] + part[3][l];
    float inv = 1.0f / D;
    Ca[bh*2048 + j] = Cj * inv;
    Db[bh*2048 + j] = Dj * inv;
  }
}

// ---------------- KC: fused PV: hp = P @ h, relu, write cat ----------------
__global__ __launch_bounds__(256) void k_pv(const u32* __restrict__ adjw, const u16* __restrict__ hT,
                       const float* __restrict__ Aarr, const float* __restrict__ Barr,
                       const float* __restrict__ Ca, const float* __restrict__ Db,
                       u16* __restrict__ cat){
  int it = blockIdx.x;           // 32 i-tiles of 64
  int bh = blockIdx.y;           // 16
  int b = bh >> 2, h = bh & 3;
  int w = threadIdx.x >> 6, l = threadIdx.x & 63;

  __shared__ u32 maskw[64*68];        // padded stride 68 words
  __shared__ u16 hTl[64*136];         // [f][j] padded stride 136 bf16
  __shared__ float CaL[128], DbL[128];

  {  // load mask strip: 64 rows x 64 words, once per block
    int row = threadIdx.x >> 2, seg = (threadIdx.x & 3) * 16;
    const u32* src = adjw + (size_t)(it*64 + row)*64 + seg;
    u32* d = maskw + row*68 + seg;
    *(uint4*)(d)      = *(const uint4*)(src);
    *(uint4*)(d + 4)  = *(const uint4*)(src + 4);
    *(uint4*)(d + 8)  = *(const uint4*)(src + 8);
    *(uint4*)(d + 12) = *(const uint4*)(src + 12);
  }

  int i_l = it*64 + w*16 + (l & 15);
  float Ai = Aarr[bh*2048 + i_l];
  float Bi = Barr[bh*2048 + i_l];
  const float* Ca_row = Ca + bh*2048;
  const float* Db_row = Db + bh*2048;
  const u16* hTrow = hT + (size_t)bh * 64 * 2048;
  int kg = (l >> 4) * 8;
  f32x4 acc[4] = {};

  for (int jc = 0; jc < 2048; jc += 128){
    __syncthreads();
    {  // stage hT tile [64 f][128 j] + Ca/Db slices
      int f = threadIdx.x >> 2, seg = (threadIdx.x & 3) * 32;
      const u16* src = hTrow + (size_t)f*2048 + jc + seg;
      u16* d = hTl + f*136 + seg;
      *(uint4*)(d)      = *(const uint4*)(src);
      *(uint4*)(d + 8)  = *(const uint4*)(src + 8);
      *(uint4*)(d + 16) = *(const uint4*)(src + 16);
      *(uint4*)(d + 24) = *(const uint4*)(src + 24);
      if (threadIdx.x < 64)       *(float2*)&CaL[threadIdx.x*2] = *(const float2*)(Ca_row + jc + threadIdx.x*2);
      else if (threadIdx.x < 128) { int t2 = threadIdx.x - 64; *(float2*)&DbL[t2*2] = *(const float2*)(Db_row + jc + t2*2); }
    }
    __syncthreads();
    #pragma unroll
    for (int ks = 0; ks < 4; ks++){
      float ca[8], db[8];
      *(float4*)(ca)     = *(const float4*)&CaL[ks*32 + kg];
      *(float4*)(ca + 4) = *(const float4*)&CaL[ks*32 + kg + 4];
      *(float4*)(db)     = *(const float4*)&DbL[ks*32 + kg];
      *(float4*)(db + 4) = *(const float4*)&DbL[ks*32 + kg + 4];
      u32 wrd = maskw[(w*16 + (l & 15))*68 + (jc >> 5) + ks];
      float wv[8];
      #pragma unroll
      for (int e = 0; e < 8; e++){
        float ev = fmaxf(Ai*ca[e], Bi*db[e]);
        wv[e] = ev * (float)((wrd >> (kg + e)) & 1u);
      }
      union{u32 w[4]; short8 v;} A;
      A.w[0] = pkbf(wv[0], wv[1]); A.w[1] = pkbf(wv[2], wv[3]);
      A.w[2] = pkbf(wv[4], wv[5]); A.w[3] = pkbf(wv[6], wv[7]);
      #pragma unroll
      for (int q = 0; q < 4; q++){
        const short8* bp = (const short8*)&hTl[(q*16 + (l & 15))*136 + ks*32 + kg];
        acc[q] = __builtin_amdgcn_mfma_f32_16x16x32_bf16(A.v, *bp, acc[q], 0, 0, 0);
      }
    }
  }
  // epilogue: relu, store cat[b][n][h*64+f] bf16
  int nb = it*64 + w*16 + (l >> 4)*4;
  #pragma unroll
  for (int q = 0; q < 4; q++){
    int f = q*16 + (l & 15);
    #pragma unroll
    for (int r = 0; r < 4; r++){
      float v = fmaxf(acc[q][r], 0.f);
      cat[((size_t)(b*2048 + nb + r))*256 + h*64 + f] = f2bf(v);
    }
  }
}

// ---------------- KD: out = leaky(cat @ Wl^T + bl) ----------------
__global__ __launch_bounds__(256) void k_out(const u16* __restrict__ cat,
                       const u16* __restrict__ Wlb, const float* __restrict__ bl,
                       float* __restrict__ out){
  int rt = blockIdx.x;   // 128 row tiles
  int w = threadIdx.x >> 6, l = threadIdx.x & 63;
  int rA = rt*64 + w*16 + (l & 15);
  int kg = (l >> 4) * 8;
  f32x4 acc[4] = {};
  #pragma unroll
  for (int ks = 0; ks < 8; ks++){
    int c = ks*32 + kg;
    short8 Af = *(const short8*)(cat + (size_t)rA*256 + c);
    #pragma unroll
    for (int q = 0; q < 4; q++){
      short8 Bf = *(const short8*)(Wlb + (size_t)(q*16 + (l & 15))*256 + c);
      acc[q] = __builtin_amdgcn_mfma_f32_16x16x32_bf16(Af, Bf, acc[q], 0, 0, 0);
    }
  }
  int rb = rt*64 + w*16 + (l >> 4)*4;
  #pragma unroll
  for (int q = 0; q < 4; q++){
    int o = q*16 + (l & 15);
    float bv = bl[o];
    #pragma unroll
    for (int r = 0; r < 4; r++){
      float v = acc[q][r] + bv;
      out[(size_t)(rb + r)*64 + o] = fmaxf(v, 0.2f*v);
    }
  }
}

extern "C" void kernel_launch(void* const* d_in, const int* in_sizes, int n_in,
                              void* d_out, int out_size, void* d_ws, size_t ws_size,
                              hipStream_t stream) {
  const float* x  = (const float*)d_in[0];
  const int* adj  = (const int*)d_in[1];
  const float* W  = (const float*)d_in[2];
  const float* a1 = (const float*)d_in[3];
  const float* a2 = (const float*)d_in[4];
  const float* Wl = (const float*)d_in[5];
  const float* bl = (const float*)d_in[6];
  float* out = (float*)d_out;
  char* ws = (char*)d_ws;

  u32* adjw  = (u32*)(ws + 0x000000);
  u16* hT    = (u16*)(ws + 0x080000);
  u16* cat   = (u16*)(ws + 0x480000);
  float* Aarr= (float*)(ws + 0x880000);
  float* Barr= (float*)(ws + 0x8A0000);
  float* f2a = (float*)(ws + 0x8C0000);
  float* f2b = (float*)(ws + 0x8E0000);
  float* Ca  = (float*)(ws + 0x900000);
  float* Db  = (float*)(ws + 0x920000);
  u16* WT    = (u16*)(ws + 0x940000);
  u16* Wlb   = (u16*)(ws + 0x960000);

  k_pre<<<16576, 256, 0, stream>>>(adj, x, W, a1, a2, Wl, adjw, Aarr, Barr, f2a, f2b, WT, Wlb);
  k_mid<<<1024, 256, 0, stream>>>(x, WT, hT, adjw, Aarr, Barr, f2a, f2b, Ca, Db);
  k_pv<<<dim3(32, 16), 256, 0, stream>>>(adjw, hT, Aarr, Barr, Ca, Db, cat);
  k_out<<<128, 256, 0, stream>>>(cat, Wlb, bl, out);
}

// Round 3
// 84.797 us; speedup vs baseline: 1.6119x; 1.6119x over previous
//
#include <hip/hip_runtime.h>
#include <hip/hip_bf16.h>
#include <stdint.h>

typedef __attribute__((ext_vector_type(8))) short short8;
typedef __attribute__((ext_vector_type(4))) float f32x4;
typedef uint32_t u32;
typedef uint16_t u16;
typedef uint8_t u8;

#define LOG2E 1.4426950408889634f

// B=4, N=2048, Cin=256, F=64, H=4
// Pipeline (5 kernels):
//  K1 k_pre : pack adj bits (byte-wise, 8 elems/thread) | WT/Wlb bf16 cvt
//  K2 k_proj: h = x@W per head (MFMA) -> hT bf16; FUSED exact-fp32 fdots from
//             accumulators -> Aarr/Barr (exp2 of f1 terms), Cexp/Dexp (exp2 of f2 terms)
//  K3 k_colsum: D_j = sum_i bit*max(A_i*C_j, B_i*D_j) -> CD packed bf16 (Ca|Db)/D
//  K4 k_pv  : P in-register from A,B,CD + mask; MFMA PV; relu -> cat bf16
//  K5 k_out : out = leaky(cat @ Wl^T + bl)
//
// ws layout (bytes):
//  adjw : 0x000000 u32[2048*64]      512KB  packed adjacency bits (bit j%32 of word [i][j/32])
//  hT   : 0x080000 bf16[16][64][2048] 4MB   per-(b,h) h transposed [f][n]
//  cat  : 0x480000 bf16[4][2048][256] 4MB   relu(hp) concat heads
//  Aarr : 0x880000 f32[16][2048]     128KB  exp2(f1*log2e)
//  Barr : 0x8A0000 f32               128KB  exp2(0.2*f1*log2e)
//  Cexp : 0x8C0000 f32               128KB  exp2(f2*log2e)
//  Dexp : 0x8E0000 f32               128KB  exp2(0.2*f2*log2e)
//  CD   : 0x900000 u32[16][2048]     128KB  packed (bf16 Ca | bf16 Db), both /D_j
//  WT   : 0x940000 bf16[4][64][256]  128KB  W transposed [h][f][c]
//  Wlb  : 0x960000 bf16[64][256]      32KB

__device__ __forceinline__ u16 f2bf(float f){
  union{float f; u32 u;} x; x.f = f;
  u32 r = x.u + 0x7FFFu + ((x.u >> 16) & 1u);
  return (u16)(r >> 16);
}
__device__ __forceinline__ u32 pkbf(float a, float b){
  __hip_bfloat162 h = __float22bfloat162_rn(float2{a, b});
  union{ __hip_bfloat162 h; u32 u; } cv; cv.h = h;
  return cv.u;
}
__device__ __forceinline__ float bflo(u32 cd){ union{u32 u; float f;} v; v.u = cd << 16; return v.f; }
__device__ __forceinline__ float bfhi(u32 cd){ union{u32 u; float f;} v; v.u = cd & 0xFFFF0000u; return v.f; }

// ---------------- K1: pack (2048 blocks) + prep (64 blocks) ----------------
__global__ __launch_bounds__(256) void k_pre(const int* __restrict__ adj,
      const float* __restrict__ W, const float* __restrict__ Wl,
      u8* __restrict__ adjb, u16* __restrict__ WT, u16* __restrict__ Wlb){
  int bid = blockIdx.x, t = threadIdx.x;
  if (bid < 2048){                    // pack: 8 adj elems -> 1 byte per thread
    int tt = bid*256 + t;
    const int4* ap = (const int4*)(adj + (size_t)tt*8);
    int4 v0 = ap[0], v1 = ap[1];
    u32 byte = (u32)(v0.x > 0)       | ((u32)(v0.y > 0) << 1)
             | ((u32)(v0.z > 0) << 2) | ((u32)(v0.w > 0) << 3)
             | ((u32)(v1.x > 0) << 4) | ((u32)(v1.y > 0) << 5)
             | ((u32)(v1.z > 0) << 6) | ((u32)(v1.w > 0) << 7);
    adjb[tt] = (u8)byte;
    return;
  }
  int tt = (bid - 2048)*256 + t;      // prep: WT / Wlb bf16
  for (int i = tt; i < 4*64*256; i += 16384){
    int h = i >> 14, f = (i >> 8) & 63, c = i & 255;
    WT[i] = f2bf(W[(h*256 + c)*64 + f]);
  }
  for (int i = tt; i < 64*256; i += 16384) Wlb[i] = f2bf(Wl[i]);
}

// ---------------- K2: proj + fused exact fdots ----------------
__global__ __launch_bounds__(256) void k_proj(const float* __restrict__ x,
      const u16* __restrict__ WT, const float* __restrict__ a1, const float* __restrict__ a2,
      u16* __restrict__ hT, float* __restrict__ Aarr, float* __restrict__ Barr,
      float* __restrict__ Cexp, float* __restrict__ Dexp){
  int rt = blockIdx.x;               // 128 row tiles of 64
  int cb = blockIdx.y;               // 4 heads
  int w = threadIdx.x >> 6, l = threadIdx.x & 63;
  int rA = rt*64 + w*16 + (l & 15);
  int kg = (l >> 4) * 8;
  f32x4 acc[4] = {};
  const float* xrow = x + (size_t)rA * 256;
  #pragma unroll
  for (int ks = 0; ks < 8; ks++){
    int c = ks*32 + kg;
    float4 xa = *(const float4*)(xrow + c);
    float4 xb = *(const float4*)(xrow + c + 4);
    union{u32 w[4]; short8 v;} A;
    A.w[0] = pkbf(xa.x, xa.y); A.w[1] = pkbf(xa.z, xa.w);
    A.w[2] = pkbf(xb.x, xb.y); A.w[3] = pkbf(xb.z, xb.w);
    #pragma unroll
    for (int q = 0; q < 4; q++){
      int col = cb*64 + q*16 + (l & 15);
      short8 Bf = *(const short8*)(WT + (size_t)col*256 + c);
      acc[q] = __builtin_amdgcn_mfma_f32_16x16x32_bf16(A.v, Bf, acc[q], 0, 0, 0);
    }
  }
  // ---- store hT (bf16) ----
  int rb = rt*64 + w*16 + (l >> 4)*4;
  int b = rb >> 11, n = rb & 2047;
  #pragma unroll
  for (int q = 0; q < 4; q++){
    int fp = cb*64 + q*16 + (l & 15);
    u32 p0 = pkbf(acc[q][0], acc[q][1]);
    u32 p1 = pkbf(acc[q][2], acc[q][3]);
    u16* dst = hT + ((size_t)(b*4 + (fp >> 6))*64 + (fp & 63))*2048 + n;
    *(uint2*)dst = uint2{p0, p1};
  }
  // ---- fused fdots: f1/f2 from fp32 accumulators (exact) ----
  float a1v[4], a2v[4];
  #pragma unroll
  for (int q = 0; q < 4; q++){
    a1v[q] = a1[cb*64 + q*16 + (l & 15)];
    a2v[q] = a2[cb*64 + q*16 + (l & 15)];
  }
  float s1[4], s2[4];
  #pragma unroll
  for (int r = 0; r < 4; r++){
    s1[r] = acc[0][r]*a1v[0] + acc[1][r]*a1v[1] + acc[2][r]*a1v[2] + acc[3][r]*a1v[3];
    s2[r] = acc[0][r]*a2v[0] + acc[1][r]*a2v[1] + acc[2][r]*a2v[2] + acc[3][r]*a2v[3];
  }
  #pragma unroll
  for (int m = 1; m <= 8; m <<= 1){
    #pragma unroll
    for (int r = 0; r < 4; r++){
      s1[r] += __shfl_xor(s1[r], m);
      s2[r] += __shfl_xor(s2[r], m);
    }
  }
  if ((l & 15) == 0){
    #pragma unroll
    for (int r = 0; r < 4; r++){
      int row = rb + r;               // rb already = rt*64 + w*16 + (l>>4)*4
      int bb = row >> 11, nn = row & 2047;
      int o = (bb*4 + cb)*2048 + nn;
      float fa = s1[r] * LOG2E;
      Aarr[o] = __builtin_amdgcn_exp2f(fa);
      Barr[o] = __builtin_amdgcn_exp2f(0.2f*fa);
      float fb = s2[r] * LOG2E;
      Cexp[o] = __builtin_amdgcn_exp2f(fb);
      Dexp[o] = __builtin_amdgcn_exp2f(0.2f*fb);
    }
  }
}

// ---------------- K3: colsum -> CD packed bf16 ----------------
__global__ __launch_bounds__(256) void k_colsum(const u32* __restrict__ adjw,
      const float* __restrict__ Aarr, const float* __restrict__ Barr,
      const float* __restrict__ Cexp, const float* __restrict__ Dexp,
      u32* __restrict__ CD){
  __shared__ float AL[2048], BL[2048];
  __shared__ float part[4][64];
  int jt = blockIdx.x;      // 32 tiles of 64 j
  int bh = blockIdx.y;      // 16
  int t = threadIdx.x;
  int w = t >> 6, l = t & 63;
  {
    const float4* As = (const float4*)(Aarr + bh*2048);
    const float4* Bs = (const float4*)(Barr + bh*2048);
    ((float4*)AL)[t]       = As[t];
    ((float4*)AL)[t + 256] = As[t + 256];
    ((float4*)BL)[t]       = Bs[t];
    ((float4*)BL)[t + 256] = Bs[t + 256];
  }
  int j = jt*64 + l;
  float Cj = Cexp[bh*2048 + j];
  float Dj = Dexp[bh*2048 + j];
  int wi = jt*2 + (l >> 5), sh = l & 31;
  __syncthreads();
  const u32* aw = adjw + wi;
  float acc0 = 0.f, acc1 = 0.f, acc2 = 0.f, acc3 = 0.f;
  int i0 = w * 512;
  #pragma unroll 4
  for (int i = i0; i < i0 + 512; i += 4){
    u32 w0 = aw[(size_t)(i+0)*64];
    u32 w1 = aw[(size_t)(i+1)*64];
    u32 w2 = aw[(size_t)(i+2)*64];
    u32 w3 = aw[(size_t)(i+3)*64];
    float v0 = fmaxf(AL[i+0]*Cj, BL[i+0]*Dj);
    float v1 = fmaxf(AL[i+1]*Cj, BL[i+1]*Dj);
    float v2 = fmaxf(AL[i+2]*Cj, BL[i+2]*Dj);
    float v3 = fmaxf(AL[i+3]*Cj, BL[i+3]*Dj);
    acc0 = fmaf(v0, (float)((w0 >> sh) & 1u), acc0);
    acc1 = fmaf(v1, (float)((w1 >> sh) & 1u), acc1);
    acc2 = fmaf(v2, (float)((w2 >> sh) & 1u), acc2);
    acc3 = fmaf(v3, (float)((w3 >> sh) & 1u), acc3);
  }
  part[w][l] = (acc0 + acc1) + (acc2 + acc3);
  __syncthreads();
  if (t < 64){
    float D = (part[0][l] + part[1][l]) + (part[2][l] + part[3][l]);
    float inv = 1.0f / D;
    CD[bh*2048 + j] = pkbf(Cj * inv, Dj * inv);
  }
}

// ---------------- K4: fused PV (128-row blocks, 8 waves) ----------------
__global__ __launch_bounds__(512) void k_pv(const u32* __restrict__ adjw, const u16* __restrict__ hT,
      const float* __restrict__ Aarr, const float* __restrict__ Barr,
      const u32* __restrict__ CD, u16* __restrict__ cat){
  int it = blockIdx.x;           // 16 i-tiles of 128
  int bh = blockIdx.y;           // 16
  int b = bh >> 2, h = bh & 3;
  int t = threadIdx.x;
  int w = t >> 6, l = t & 63;

  __shared__ u32 maskw[128*68];       // 34.8KB, padded stride 68
  __shared__ u16 hTl[64*136];         // 17.4KB, [f][j] padded stride 136
  __shared__ u32 CDl[128];

  {  // load mask strip: 128 rows x 64 words
    int row = t >> 2, seg = (t & 3) * 16;
    const u32* src = adjw + (size_t)(it*128 + row)*64 + seg;
    u32* d = maskw + row*68 + seg;
    *(uint4*)(d)      = *(const uint4*)(src);
    *(uint4*)(d + 4)  = *(const uint4*)(src + 4);
    *(uint4*)(d + 8)  = *(const uint4*)(src + 8);
    *(uint4*)(d + 12) = *(const uint4*)(src + 12);
  }

  int i_l = it*128 + w*16 + (l & 15);
  float Ai = Aarr[bh*2048 + i_l];
  float Bi = Barr[bh*2048 + i_l];
  const u32* CD_row = CD + bh*2048;
  const u16* hTrow = hT + (size_t)bh * 64 * 2048;
  int kg = (l >> 4) * 8;
  f32x4 acc[4] = {};

  for (int jc = 0; jc < 2048; jc += 128){
    __syncthreads();
    {  // stage hT tile [64 f][128 j] + CD slice
      int f = t >> 3, seg = (t & 7) * 16;
      const u16* src = hTrow + (size_t)f*2048 + jc + seg;
      u16* d = hTl + f*136 + seg;
      *(uint4*)(d)     = *(const uint4*)(src);
      *(uint4*)(d + 8) = *(const uint4*)(src + 8);
      if (t >= 256 && t < 320){
        int t2 = t - 256;
        *(uint2*)&CDl[t2*2] = *(const uint2*)(CD_row + jc + t2*2);
      }
    }
    __syncthreads();
    #pragma unroll
    for (int ks = 0; ks < 4; ks++){
      u32 cd[8];
      *(uint4*)(cd)     = *(const uint4*)&CDl[ks*32 + kg];
      *(uint4*)(cd + 4) = *(const uint4*)&CDl[ks*32 + kg + 4];
      u32 wrd = maskw[(w*16 + (l & 15))*68 + (jc >> 5) + ks];
      float wv[8];
      #pragma unroll
      for (int e = 0; e < 8; e++){
        float ev = fmaxf(Ai*bflo(cd[e]), Bi*bfhi(cd[e]));
        wv[e] = ev * (float)((wrd >> (kg + e)) & 1u);
      }
      union{u32 w[4]; short8 v;} A;
      A.w[0] = pkbf(wv[0], wv[1]); A.w[1] = pkbf(wv[2], wv[3]);
      A.w[2] = pkbf(wv[4], wv[5]); A.w[3] = pkbf(wv[6], wv[7]);
      #pragma unroll
      for (int q = 0; q < 4; q++){
        const short8* bp = (const short8*)&hTl[(q*16 + (l & 15))*136 + ks*32 + kg];
        acc[q] = __builtin_amdgcn_mfma_f32_16x16x32_bf16(A.v, *bp, acc[q], 0, 0, 0);
      }
    }
  }
  // epilogue: relu, store cat[b][n][h*64+f] bf16
  int nb = it*128 + w*16 + (l >> 4)*4;
  #pragma unroll
  for (int q = 0; q < 4; q++){
    int f = q*16 + (l & 15);
    #pragma unroll
    for (int r = 0; r < 4; r++){
      float v = fmaxf(acc[q][r], 0.f);
      cat[((size_t)(b*2048 + nb + r))*256 + h*64 + f] = f2bf(v);
    }
  }
}

// ---------------- K5: out = leaky(cat @ Wl^T + bl) ----------------
__global__ __launch_bounds__(256) void k_out(const u16* __restrict__ cat,
                       const u16* __restrict__ Wlb, const float* __restrict__ bl,
                       float* __restrict__ out){
  int rt = blockIdx.x;   // 128 row tiles
  int w = threadIdx.x >> 6, l = threadIdx.x & 63;
  int rA = rt*64 + w*16 + (l & 15);
  int kg = (l >> 4) * 8;
  f32x4 acc[4] = {};
  #pragma unroll
  for (int ks = 0; ks < 8; ks++){
    int c = ks*32 + kg;
    short8 Af = *(const short8*)(cat + (size_t)rA*256 + c);
    #pragma unroll
    for (int q = 0; q < 4; q++){
      short8 Bf = *(const short8*)(Wlb + (size_t)(q*16 + (l & 15))*256 + c);
      acc[q] = __builtin_amdgcn_mfma_f32_16x16x32_bf16(Af, Bf, acc[q], 0, 0, 0);
    }
  }
  int rb = rt*64 + w*16 + (l >> 4)*4;
  #pragma unroll
  for (int q = 0; q < 4; q++){
    int o = q*16 + (l & 15);
    float bv = bl[o];
    #pragma unroll
    for (int r = 0; r < 4; r++){
      float v = acc[q][r] + bv;
      out[(size_t)(rb + r)*64 + o] = fmaxf(v, 0.2f*v);
    }
  }
}

extern "C" void kernel_launch(void* const* d_in, const int* in_sizes, int n_in,
                              void* d_out, int out_size, void* d_ws, size_t ws_size,
                              hipStream_t stream) {
  const float* x  = (const float*)d_in[0];
  const int* adj  = (const int*)d_in[1];
  const float* W  = (const float*)d_in[2];
  const float* a1 = (const float*)d_in[3];
  const float* a2 = (const float*)d_in[4];
  const float* Wl = (const float*)d_in[5];
  const float* bl = (const float*)d_in[6];
  float* out = (float*)d_out;
  char* ws = (char*)d_ws;

  u32* adjw  = (u32*)(ws + 0x000000);
  u16* hT    = (u16*)(ws + 0x080000);
  u16* cat   = (u16*)(ws + 0x480000);
  float* Aarr= (float*)(ws + 0x880000);
  float* Barr= (float*)(ws + 0x8A0000);
  float* Cexp= (float*)(ws + 0x8C0000);
  float* Dexp= (float*)(ws + 0x8E0000);
  u32* CD    = (u32*)(ws + 0x900000);
  u16* WT    = (u16*)(ws + 0x940000);
  u16* Wlb   = (u16*)(ws + 0x960000);

  k_pre<<<2112, 256, 0, stream>>>(adj, W, Wl, (u8*)adjw, WT, Wlb);
  k_proj<<<dim3(128, 4), 256, 0, stream>>>(x, WT, a1, a2, hT, Aarr, Barr, Cexp, Dexp);
  k_colsum<<<dim3(32, 16), 256, 0, stream>>>(adjw, Aarr, Barr, Cexp, Dexp, CD);
  k_pv<<<dim3(16, 16), 512, 0, stream>>>(adjw, hT, Aarr, Barr, CD, cat);
  k_out<<<128, 256, 0, stream>>>(cat, Wlb, bl, out);
}

// Round 4
// 81.178 us; speedup vs baseline: 1.6838x; 1.0446x over previous
//
#include <hip/hip_runtime.h>
#include <hip/hip_bf16.h>
#include <stdint.h>

typedef __attribute__((ext_vector_type(8))) short short8;
typedef __attribute__((ext_vector_type(4))) float f32x4;
typedef uint32_t u32;
typedef uint16_t u16;
typedef uint8_t u8;

#define LOG2E 1.4426950408889634f

// B=4, N=2048, Cin=256, F=64, H=4
// Pipeline (4 kernels):
//  K1 k_front : proj (x@W per head via MFMA, W transposed block-locally in LDS)
//               + fused exact-fp32 fdots -> Aarr/Barr/Cexp/Dexp  ||  pack adj bits
//  K2 k_colsum: D_j = sum_i bit*max(A_i*C_j, B_i*D_j) -> CD packed bf16 (C|D)/D_j
//  K3 k_pv    : P in-register (32 i/wave, mask+CD from L2, B-frags reused 2x),
//               j-split halves -> f32 partials
//  K4 k_out   : out = leaky((relu(p0+p1) @ Wl^T) + bl), Wl converted inline
//
// ws layout (bytes):
//  adjw : 0x0000000 u32[2048*64]       512KB  packed adjacency bits
//  hT   : 0x0080000 bf16[16][64][2048]   4MB  per-(b,h) h transposed [f][n]
//  part : 0x0480000 f32[2][4][2048][256] 16MB hp partial sums (2 j-halves)
//  Aarr : 0x1480000 f32[16][2048]      128KB  exp2(f1*log2e)
//  Barr : 0x14A0000 f32                128KB  exp2(0.2*f1*log2e)
//  Cexp : 0x14C0000 f32                128KB  exp2(f2*log2e)
//  Dexp : 0x14E0000 f32                128KB  exp2(0.2*f2*log2e)
//  CD   : 0x1500000 u32[16][2048]      128KB  packed (bf16 C/D | bf16 Dbar/D)

__device__ __forceinline__ u16 f2bf(float f){
  union{float f; u32 u;} x; x.f = f;
  u32 r = x.u + 0x7FFFu + ((x.u >> 16) & 1u);
  return (u16)(r >> 16);
}
__device__ __forceinline__ u32 pkbf(float a, float b){
  __hip_bfloat162 h = __float22bfloat162_rn(float2{a, b});
  union{ __hip_bfloat162 h; u32 u; } cv; cv.h = h;
  return cv.u;
}
__device__ __forceinline__ float bflo(u32 cd){ union{u32 u; float f;} v; v.u = cd << 16; return v.f; }
__device__ __forceinline__ float bfhi(u32 cd){ union{u32 u; float f;} v; v.u = cd & 0xFFFF0000u; return v.f; }

// ---------------- K1: proj(+fdots) || pack ----------------
__global__ __launch_bounds__(256) void k_front(const float* __restrict__ x,
      const float* __restrict__ W, const float* __restrict__ a1, const float* __restrict__ a2,
      const int* __restrict__ adj,
      u8* __restrict__ adjb, u16* __restrict__ hT,
      float* __restrict__ Aarr, float* __restrict__ Barr,
      float* __restrict__ Cexp, float* __restrict__ Dexp){
  int bid = blockIdx.x, t = threadIdx.x;

  if (bid >= 512){                    // ---- pack: 8 adj elems -> 1 byte ----
    int idx = (bid - 512)*256 + t;
    const int4* ap = (const int4*)(adj + (size_t)idx*8);
    int4 v0 = ap[0], v1 = ap[1];
    u32 byte = (u32)(v0.x > 0)        | ((u32)(v0.y > 0) << 1)
             | ((u32)(v0.z > 0) << 2) | ((u32)(v0.w > 0) << 3)
             | ((u32)(v1.x > 0) << 4) | ((u32)(v1.y > 0) << 5)
             | ((u32)(v1.z > 0) << 6) | ((u32)(v1.w > 0) << 7);
    adjb[idx] = (u8)byte;
    return;
  }
  // ---- proj: h = x @ W[head cb]; block-local W transpose in LDS ----
  __shared__ u16 WL[64*264];          // [f][c] stride 264 elems (528B, 16B-aligned, 2-way banks)
  int rt = bid & 127, cb = bid >> 7;
  const float* Wh = W + (size_t)cb*16384;     // [256 c][64 f]
  #pragma unroll 4
  for (int p = 0; p < 16; p++){
    int idx = p*256 + t;              // float4 index over 16384 f32
    float4 wv = ((const float4*)Wh)[idx];
    int off = idx*4; int c = off >> 6, f0 = off & 63;
    WL[(f0+0)*264 + c] = f2bf(wv.x);
    WL[(f0+1)*264 + c] = f2bf(wv.y);
    WL[(f0+2)*264 + c] = f2bf(wv.z);
    WL[(f0+3)*264 + c] = f2bf(wv.w);
  }
  __syncthreads();

  int w = t >> 6, l = t & 63;
  int rA = rt*64 + w*16 + (l & 15);
  int kg = (l >> 4) * 8;
  f32x4 acc[4] = {};
  const float* xrow = x + (size_t)rA * 256;
  #pragma unroll
  for (int ks = 0; ks < 8; ks++){
    int c = ks*32 + kg;
    float4 xa = *(const float4*)(xrow + c);
    float4 xb = *(const float4*)(xrow + c + 4);
    union{u32 w[4]; short8 v;} A;
    A.w[0] = pkbf(xa.x, xa.y); A.w[1] = pkbf(xa.z, xa.w);
    A.w[2] = pkbf(xb.x, xb.y); A.w[3] = pkbf(xb.z, xb.w);
    #pragma unroll
    for (int q = 0; q < 4; q++){
      short8 Bf = *(const short8*)&WL[(q*16 + (l & 15))*264 + c];
      acc[q] = __builtin_amdgcn_mfma_f32_16x16x32_bf16(A.v, Bf, acc[q], 0, 0, 0);
    }
  }
  // store hT (bf16) [bh][f][n]
  int rb = rt*64 + w*16 + (l >> 4)*4;
  int b = rb >> 11, n = rb & 2047;
  #pragma unroll
  for (int q = 0; q < 4; q++){
    int f = q*16 + (l & 15);
    u32 p0 = pkbf(acc[q][0], acc[q][1]);
    u32 p1 = pkbf(acc[q][2], acc[q][3]);
    u16* dst = hT + ((size_t)(b*4 + cb)*64 + f)*2048 + n;
    *(uint2*)dst = uint2{p0, p1};
  }
  // fused fdots: exact fp32 f1/f2 from accumulators
  float a1v[4], a2v[4];
  #pragma unroll
  for (int q = 0; q < 4; q++){
    a1v[q] = a1[cb*64 + q*16 + (l & 15)];
    a2v[q] = a2[cb*64 + q*16 + (l & 15)];
  }
  float s1[4], s2[4];
  #pragma unroll
  for (int r = 0; r < 4; r++){
    s1[r] = acc[0][r]*a1v[0] + acc[1][r]*a1v[1] + acc[2][r]*a1v[2] + acc[3][r]*a1v[3];
    s2[r] = acc[0][r]*a2v[0] + acc[1][r]*a2v[1] + acc[2][r]*a2v[2] + acc[3][r]*a2v[3];
  }
  #pragma unroll
  for (int m = 1; m <= 8; m <<= 1){
    #pragma unroll
    for (int r = 0; r < 4; r++){
      s1[r] += __shfl_xor(s1[r], m);
      s2[r] += __shfl_xor(s2[r], m);
    }
  }
  if ((l & 15) == 0){
    #pragma unroll
    for (int r = 0; r < 4; r++){
      int row = rb + r;
      int bb = row >> 11, nn = row & 2047;
      int o = (bb*4 + cb)*2048 + nn;
      float fa = s1[r] * LOG2E;
      Aarr[o] = __builtin_amdgcn_exp2f(fa);
      Barr[o] = __builtin_amdgcn_exp2f(0.2f*fa);
      float fb = s2[r] * LOG2E;
      Cexp[o] = __builtin_amdgcn_exp2f(fb);
      Dexp[o] = __builtin_amdgcn_exp2f(0.2f*fb);
    }
  }
}

// ---------------- K2: colsum -> CD packed bf16 ----------------
__global__ __launch_bounds__(256) void k_colsum(const u32* __restrict__ adjw,
      const float* __restrict__ Aarr, const float* __restrict__ Barr,
      const float* __restrict__ Cexp, const float* __restrict__ Dexp,
      u32* __restrict__ CD){
  __shared__ float AL[2048], BL[2048];
  __shared__ float part[4][64];
  int jt = blockIdx.x;      // 32 tiles of 64 j
  int bh = blockIdx.y;      // 16
  int t = threadIdx.x;
  int w = t >> 6, l = t & 63;
  {
    const float4* As = (const float4*)(Aarr + bh*2048);
    const float4* Bs = (const float4*)(Barr + bh*2048);
    ((float4*)AL)[t]       = As[t];
    ((float4*)AL)[t + 256] = As[t + 256];
    ((float4*)BL)[t]       = Bs[t];
    ((float4*)BL)[t + 256] = Bs[t + 256];
  }
  int j = jt*64 + l;
  float Cj = Cexp[bh*2048 + j];
  float Dj = Dexp[bh*2048 + j];
  int wi = jt*2 + (l >> 5);
  int shl = 31 - (l & 31);
  __syncthreads();
  const u32* aw = adjw + wi;
  float acc0 = 0.f, acc1 = 0.f;
  int i0 = w * 512;
  #pragma unroll 2
  for (int i = i0; i < i0 + 512; i += 8){
    float av[8], bv[8];
    *(float4*)(av)   = *(const float4*)&AL[i];
    *(float4*)(av+4) = *(const float4*)&AL[i+4];
    *(float4*)(bv)   = *(const float4*)&BL[i];
    *(float4*)(bv+4) = *(const float4*)&BL[i+4];
    u32 m[8];
    #pragma unroll
    for (int k = 0; k < 8; k++) m[k] = aw[(size_t)(i+k)*64];
    #pragma unroll
    for (int k = 0; k < 8; k++){
      float v = fmaxf(av[k]*Cj, bv[k]*Dj);
      float sel = ((int)(m[k] << shl) < 0) ? v : 0.f;
      if (k & 1) acc1 += sel; else acc0 += sel;
    }
  }
  part[w][l] = acc0 + acc1;
  __syncthreads();
  if (t < 64){
    float D = (part[0][l] + part[1][l]) + (part[2][l] + part[3][l]);
    float inv = 1.0f / D;
    CD[bh*2048 + j] = pkbf(Cj * inv, Dj * inv);
  }
}

// ---------------- K3: fused PV, 32 i/wave, j-split -> f32 partials ----------------
__global__ __launch_bounds__(256) void k_pv(const u32* __restrict__ adjw, const u16* __restrict__ hT,
      const float* __restrict__ Aarr, const float* __restrict__ Barr,
      const u32* __restrict__ CD, float* __restrict__ part){
  int it = blockIdx.x;           // 16 i-tiles of 128
  int bh = blockIdx.y;           // 16
  int jh = blockIdx.z;           // 2 j-halves
  int b = bh >> 2, h = bh & 3;
  int t = threadIdx.x;
  int w = t >> 6, l = t & 63;

  __shared__ u16 hTl[64*136];         // 17.4KB, [f][j] padded stride 136 bf16

  int i0 = it*128 + w*32 + (l & 15);  // row-block 0; row-block 1 = i0+16
  float Ai0 = Aarr[bh*2048 + i0],      Bi0 = Barr[bh*2048 + i0];
  float Ai1 = Aarr[bh*2048 + i0 + 16], Bi1 = Barr[bh*2048 + i0 + 16];
  const u32* CDr = CD + bh*2048;
  const u16* hTr = hT + (size_t)bh * 64 * 2048;
  int kg = (l >> 4) * 8;
  f32x4 acc[2][4] = {};

  for (int jj = 0; jj < 1024; jj += 128){
    int jc = jh*1024 + jj;
    __syncthreads();
    {  // stage hT tile [64 f][128 j]
      int f = t >> 2, seg = (t & 3) * 32;
      const u16* src = hTr + (size_t)f*2048 + jc + seg;
      u16* d = hTl + f*136 + seg;
      *(uint4*)(d)      = *(const uint4*)(src);
      *(uint4*)(d + 8)  = *(const uint4*)(src + 8);
      *(uint4*)(d + 16) = *(const uint4*)(src + 16);
      *(uint4*)(d + 24) = *(const uint4*)(src + 24);
    }
    __syncthreads();
    uint4 mw0 = *(const uint4*)(adjw + (size_t)i0*64 + (jc >> 5));
    uint4 mw1 = *(const uint4*)(adjw + (size_t)(i0+16)*64 + (jc >> 5));
    #pragma unroll
    for (int ks = 0; ks < 4; ks++){
      u32 cd[8];
      *(uint4*)(cd)     = *(const uint4*)(CDr + jc + ks*32 + kg);
      *(uint4*)(cd + 4) = *(const uint4*)(CDr + jc + ks*32 + kg + 4);
      u32 w0 = (&mw0.x)[ks] >> kg;
      u32 w1 = (&mw1.x)[ks] >> kg;
      float wv0[8], wv1[8];
      #pragma unroll
      for (int e = 0; e < 8; e++){
        float ca = bflo(cd[e]), db = bfhi(cd[e]);
        float ev0 = fmaxf(Ai0*ca, Bi0*db);
        float ev1 = fmaxf(Ai1*ca, Bi1*db);
        wv0[e] = ((int)(w0 << (31-e)) < 0) ? ev0 : 0.f;
        wv1[e] = ((int)(w1 << (31-e)) < 0) ? ev1 : 0.f;
      }
      union{u32 w[4]; short8 v;} A0, A1;
      A0.w[0] = pkbf(wv0[0], wv0[1]); A0.w[1] = pkbf(wv0[2], wv0[3]);
      A0.w[2] = pkbf(wv0[4], wv0[5]); A0.w[3] = pkbf(wv0[6], wv0[7]);
      A1.w[0] = pkbf(wv1[0], wv1[1]); A1.w[1] = pkbf(wv1[2], wv1[3]);
      A1.w[2] = pkbf(wv1[4], wv1[5]); A1.w[3] = pkbf(wv1[6], wv1[7]);
      #pragma unroll
      for (int q = 0; q < 4; q++){
        short8 Bf = *(const short8*)&hTl[(q*16 + (l & 15))*136 + ks*32 + kg];
        acc[0][q] = __builtin_amdgcn_mfma_f32_16x16x32_bf16(A0.v, Bf, acc[0][q], 0, 0, 0);
        acc[1][q] = __builtin_amdgcn_mfma_f32_16x16x32_bf16(A1.v, Bf, acc[1][q], 0, 0, 0);
      }
    }
  }
  // epilogue: write f32 partial [jh][b][n][h*64+f]
  float* pr = part + ((size_t)(jh*4 + b)*2048)*256;
  #pragma unroll
  for (int r = 0; r < 2; r++){
    int nb = it*128 + w*32 + r*16 + (l >> 4)*4;
    #pragma unroll
    for (int q = 0; q < 4; q++){
      int f = h*64 + q*16 + (l & 15);
      #pragma unroll
      for (int rr = 0; rr < 4; rr++){
        pr[(size_t)(nb + rr)*256 + f] = acc[r][q][rr];
      }
    }
  }
}

// ---------------- K4: out = leaky(relu(p0+p1) @ Wl^T + bl) ----------------
__global__ __launch_bounds__(256) void k_out(const float* __restrict__ part,
                       const float* __restrict__ Wl, const float* __restrict__ bl,
                       float* __restrict__ out){
  int rt = blockIdx.x;   // 128 row tiles
  int w = threadIdx.x >> 6, l = threadIdx.x & 63;
  int rA = rt*64 + w*16 + (l & 15);
  int b = rA >> 11, n = rA & 2047;
  const float* p0 = part + ((size_t)b*2048 + n)*256;
  const float* p1 = part + ((size_t)(4 + b)*2048 + n)*256;
  int kg = (l >> 4) * 8;
  f32x4 acc[4] = {};
  #pragma unroll
  for (int ks = 0; ks < 8; ks++){
    int c = ks*32 + kg;
    float4 x0 = *(const float4*)(p0 + c);
    float4 x1 = *(const float4*)(p0 + c + 4);
    float4 y0 = *(const float4*)(p1 + c);
    float4 y1 = *(const float4*)(p1 + c + 4);
    float av[8];
    av[0] = fmaxf(x0.x + y0.x, 0.f); av[1] = fmaxf(x0.y + y0.y, 0.f);
    av[2] = fmaxf(x0.z + y0.z, 0.f); av[3] = fmaxf(x0.w + y0.w, 0.f);
    av[4] = fmaxf(x1.x + y1.x, 0.f); av[5] = fmaxf(x1.y + y1.y, 0.f);
    av[6] = fmaxf(x1.z + y1.z, 0.f); av[7] = fmaxf(x1.w + y1.w, 0.f);
    union{u32 w[4]; short8 v;} A;
    A.w[0] = pkbf(av[0], av[1]); A.w[1] = pkbf(av[2], av[3]);
    A.w[2] = pkbf(av[4], av[5]); A.w[3] = pkbf(av[6], av[7]);
    #pragma unroll
    for (int q = 0; q < 4; q++){
      const float* wr = Wl + (size_t)(q*16 + (l & 15))*256 + c;
      float4 u0 = *(const float4*)(wr);
      float4 u1 = *(const float4*)(wr + 4);
      union{u32 w[4]; short8 v;} Bv;
      Bv.w[0] = pkbf(u0.x, u0.y); Bv.w[1] = pkbf(u0.z, u0.w);
      Bv.w[2] = pkbf(u1.x, u1.y); Bv.w[3] = pkbf(u1.z, u1.w);
      acc[q] = __builtin_amdgcn_mfma_f32_16x16x32_bf16(A.v, Bv.v, acc[q], 0, 0, 0);
    }
  }
  int rb = rt*64 + w*16 + (l >> 4)*4;
  #pragma unroll
  for (int q = 0; q < 4; q++){
    int o = q*16 + (l & 15);
    float bv = bl[o];
    #pragma unroll
    for (int r = 0; r < 4; r++){
      float v = acc[q][r] + bv;
      out[(size_t)(rb + r)*64 + o] = fmaxf(v, 0.2f*v);
    }
  }
}

extern "C" void kernel_launch(void* const* d_in, const int* in_sizes, int n_in,
                              void* d_out, int out_size, void* d_ws, size_t ws_size,
                              hipStream_t stream) {
  const float* x  = (const float*)d_in[0];
  const int* adj  = (const int*)d_in[1];
  const float* W  = (const float*)d_in[2];
  const float* a1 = (const float*)d_in[3];
  const float* a2 = (const float*)d_in[4];
  const float* Wl = (const float*)d_in[5];
  const float* bl = (const float*)d_in[6];
  float* out = (float*)d_out;
  char* ws = (char*)d_ws;

  u32* adjw   = (u32*)(ws + 0x0000000);
  u16* hT     = (u16*)(ws + 0x0080000);
  float* part = (float*)(ws + 0x0480000);
  float* Aarr = (float*)(ws + 0x1480000);
  float* Barr = (float*)(ws + 0x14A0000);
  float* Cexp = (float*)(ws + 0x14C0000);
  float* Dexp = (float*)(ws + 0x14E0000);
  u32* CD     = (u32*)(ws + 0x1500000);

  k_front<<<2560, 256, 0, stream>>>(x, W, a1, a2, adj, (u8*)adjw, hT, Aarr, Barr, Cexp, Dexp);
  k_colsum<<<dim3(32, 16), 256, 0, stream>>>(adjw, Aarr, Barr, Cexp, Dexp, CD);
  k_pv<<<dim3(16, 16, 2), 256, 0, stream>>>(adjw, hT, Aarr, Barr, CD, part);
  k_out<<<128, 256, 0, stream>>>(part, Wl, bl, out);
}